// Round 17
// baseline (85.236 us; speedup 1.0000x reference)
//
#include <hip/hip_runtime.h>
#include <hip/hip_bf16.h>

#define T_DIM 4096
#define H_DIM 2048
#define K_DIM 2048
#define NCHUNK 64
#define CLEN 64
#define NT32 (K_DIM / 32)

typedef float f32x4 __attribute__((ext_vector_type(4)));
typedef _Float16 f16x8 __attribute__((ext_vector_type(8)));

typedef const __attribute__((address_space(1))) char* gp1;
typedef __attribute__((address_space(3))) char* lp3;

static const size_t nX = (size_t)T_DIM * K_DIM;   // 8.4M elems
static const size_t nB = (size_t)H_DIM * K_DIM;   // 4.2M elems

// ---------------------------------------------------------------------------
// Convert pass: fp32 -> f16 (RN), PRE-SWIZZLED within 64B segments (r17:
// BK=32 tiles stage 64B per row per K-step; 16B block at byte colB ->
// (colB&~63) | ((colB&63) ^ ((row&3)<<4))). Paired with the matching XOR on
// the gemm read side (rule #21: both sides or neither).
// ---------------------------------------------------------------------------
__global__ __launch_bounds__(256) void cvt_swz_all(const float* __restrict__ X,
                                                   const float* __restrict__ Bm,
                                                   _Float16* __restrict__ Xh,
                                                   _Float16* __restrict__ Bh) {
    size_t i = ((size_t)blockIdx.x * 256 + threadIdx.x) * 8;
    const float* in;
    _Float16* out;
    size_t j;
    if (i < nX) { in = X;  out = Xh; j = i; }
    else        { in = Bm; out = Bh; j = i - nX; }
    int row  = (int)(j >> 11);
    int colB = (int)(j & 2047) * 2;                 // byte col, mult of 16
    float a[8];
    *(f32x4*)(a)     = *(const f32x4*)(in + j);
    *(f32x4*)(a + 4) = *(const f32x4*)(in + j + 4);
    f16x8 h;
#pragma unroll
    for (int k = 0; k < 8; ++k) h[k] = (_Float16)a[k];
    unsigned sw = (unsigned)(colB & ~63) | (((unsigned)colB & 63u) ^ (((unsigned)row & 3u) << 4));
    size_t ob = (size_t)row * 4096 + sw;
    *(f16x8*)((char*)out + ob) = h;
}

// ---------------------------------------------------------------------------
// f16 GEMM, Y = X @ B^T, 128x128 tile, BK=32, 8 waves (512 thr) 2M x 4N
// (wave 64x32, acc[4][2]), prefetch dbuf + plain __syncthreads.
// r17 probe: 32KB LDS/block + VGPR<=64 (launch_bounds(512,8)) -> 4 blocks/CU
// = 32 waves/CU. Same total staging traffic as BK=64: discriminates
// latency-bound (expect ~35us) vs cache-BW-bound (expect ~40, revert).
// Y written f16 (r14). Epilogue: e[c][h] from fp32 accumulators (r9 form).
// ---------------------------------------------------------------------------
__global__ __launch_bounds__(512, 8) void gemm_f16(const _Float16* __restrict__ Xh,
                                                   const _Float16* __restrict__ Bh,
                                                   const float* __restrict__ lamda,
                                                   _Float16* __restrict__ Yh,
                                                   float* __restrict__ e) {
    __shared__ __align__(16) _Float16 sA[2][128 * 32];   // 8 KB each buf
    __shared__ __align__(16) _Float16 sB[2][128 * 32];

    int bid = blockIdx.x;
    int swz = (bid & 7) * 64 + (bid >> 3);    // bijective: 512 % 8 == 0
    const int h0 = (swz & 15) * 128;
    const int t0 = (swz >> 4) * 128;

    const int tid  = threadIdx.x;             // 0..511
    const int lane = tid & 63;
    const int wave = tid >> 6;                // 0..7
    const int wrow = wave >> 2;               // 0..1 : 64-row band (= chunk)
    const int wcol = wave & 3;                // 0..3 : 32-col band
    const int ln15 = lane & 15;
    const int kq   = lane >> 4;

    f32x4 acc[4][2] = {};

    // staging: 1 A-load + 1 B-load per thread (512 16B slots per matrix)
    const int srow = tid >> 2;                // 0..127
    const int kcB  = (tid & 3) * 16;
    const size_t gA0 = (size_t)(t0 + srow) * 4096 + kcB;
    const size_t gB0 = (size_t)(h0 + srow) * 4096 + kcB;
    const unsigned ldsOff = (unsigned)(wave * 1024);   // wave-uniform base

    // fragment byte offsets: row stride 64B, XOR (row&3)<<4 within segment
    int offA[4], offB[2];
#pragma unroll
    for (int m = 0; m < 4; ++m) {
        int rA = wrow * 64 + m * 16 + ln15;
        offA[m] = rA * 64 + ((kq * 16) ^ ((rA & 3) << 4));
    }
#pragma unroll
    for (int n = 0; n < 2; ++n) {
        int rB = wcol * 32 + n * 16 + ln15;
        offB[n] = rB * 64 + ((kq * 16) ^ ((rB & 3) << 4));
    }

#define STAGE(buf, kt)                                                                   \
    {                                                                                    \
        __builtin_amdgcn_global_load_lds((gp1)((const char*)Xh + gA0 + (kt) * 64),       \
                                         (lp3)((char*)sA[buf] + ldsOff), 16, 0, 0);      \
        __builtin_amdgcn_global_load_lds((gp1)((const char*)Bh + gB0 + (kt) * 64),       \
                                         (lp3)((char*)sB[buf] + ldsOff), 16, 0, 0);      \
    }

#define COMPUTE(buf)                                                                     \
    {                                                                                    \
        const char* pA = (const char*)sA[buf];                                           \
        const char* pB = (const char*)sB[buf];                                           \
        f16x8 fa[4], fb[2];                                                              \
        _Pragma("unroll")                                                                \
        for (int m = 0; m < 4; ++m) fa[m] = *(const f16x8*)(pA + offA[m]);               \
        _Pragma("unroll")                                                                \
        for (int n = 0; n < 2; ++n) fb[n] = *(const f16x8*)(pB + offB[n]);               \
        _Pragma("unroll")                                                                \
        for (int m = 0; m < 4; ++m)                                                      \
            _Pragma("unroll")                                                            \
            for (int n = 0; n < 2; ++n)                                                  \
                acc[m][n] = __builtin_amdgcn_mfma_f32_16x16x32_f16(fa[m], fb[n],         \
                                                                  acc[m][n], 0, 0, 0);  \
    }

    STAGE(0, 0);
    __syncthreads();

    int cur = 0;
    for (int kt = 0; kt < NT32; ++kt) {
        if (kt + 1 < NT32) STAGE(cur ^ 1, kt + 1);   // prefetch overlaps compute
        COMPUTE(cur);
        __syncthreads();                              // drains vmcnt + frees buf
        cur ^= 1;
    }
#undef STAGE
#undef COMPUTE

    // epilogue 1: Y-write (f16). C/D: col = lane&15, row = (lane>>4)*4+j
#pragma unroll
    for (int m = 0; m < 4; ++m) {
        int row = t0 + wrow * 64 + m * 16 + kq * 4;
#pragma unroll
        for (int n = 0; n < 2; ++n) {
            int col = h0 + wcol * 32 + n * 16 + ln15;
#pragma unroll
            for (int j = 0; j < 4; ++j)
                Yh[(size_t)(row + j) * H_DIM + col] = (_Float16)acc[m][n][j];
        }
    }

    // epilogue 2: e[c][h] = sum_r lam^(63-r) y[r][h] for this wave's chunk.
    // row r = m*16 + kq*4 + j -> weight lam^(16(3-m)) * lam^(4(3-kq)) * lam^(3-j)
    const int c = (t0 >> 6) + wrow;
#pragma unroll
    for (int n = 0; n < 2; ++n) {
        int col = h0 + wcol * 32 + n * 16 + ln15;
        float lam  = lamda[col];
        float lam2 = lam * lam;
        float lam4 = lam2 * lam2;
        float lam16 = lam4 * lam4 * lam4 * lam4;
        float hsum = 0.f;
#pragma unroll
        for (int m = 0; m < 4; ++m) {
            float hm = fmaf(fmaf(fmaf(acc[m][n][0], lam, acc[m][n][1]), lam,
                                 acc[m][n][2]), lam, acc[m][n][3]);
            hsum = fmaf(hsum, lam16, hm);
        }
        float w = 1.f;                         // lam4^(3-kq)
        if (kq < 3) w = lam4;
        if (kq < 2) w *= lam4;
        if (kq < 1) w *= lam4;
        float T = hsum * w;
        T += __shfl_xor(T, 16);
        T += __shfl_xor(T, 32);
        if (kq == 0) e[(size_t)c * H_DIM + col] = T;
    }
}

// ---------------------------------------------------------------------------
// Scan finish: carry prefix P[c] from e (identical fma order every block),
// seeded chunk re-scan reading f16 Y, writing final fp32 h to d_out.
// [r6: no cross-block chains; r12: no grid.sync; r13: XCD remap neutral]
// ---------------------------------------------------------------------------
__global__ __launch_bounds__(256) void scanCB(const _Float16* __restrict__ Yh,
                                              float* __restrict__ Y,
                                              const float* __restrict__ lamda,
                                              const float* __restrict__ e) {
    int c = blockIdx.x >> 3;
    int h = (blockIdx.x & 7) * 256 + threadIdx.x;
    float lam = lamda[h];
    float lamL = lam;
#pragma unroll
    for (int i = 0; i < 6; ++i) lamL *= lamL;   // lam^64
    float s = 0.f;
    for (int ci = 0; ci < c; ++ci)
        s = fmaf(lamL, s, e[(size_t)ci * H_DIM + h]);   // s == P[c]
    const _Float16* qi = Yh + (size_t)c * CLEN * H_DIM + h;
    float* qo = Y + (size_t)c * CLEN * H_DIM + h;
#pragma unroll
    for (int t = 0; t < CLEN; ++t) {
        float v = fmaf(lam, s, (float)qi[(size_t)t * H_DIM]);
        qo[(size_t)t * H_DIM] = v;
        s = v;
    }
}

// ---------------------------------------------------------------------------
// Fallback path (ws too small): register-staged hi/lo split GEMM + scans,
// all through fp32 Y in d_out. (Self-contained; own LDS swizzle.)
// ---------------------------------------------------------------------------
__global__ __launch_bounds__(256) void gemm_xbT_split(const float* __restrict__ X,
                                                      const float* __restrict__ Bm,
                                                      float* __restrict__ Y) {
    __shared__ __align__(16) _Float16 Ah[128 * 64];
    __shared__ __align__(16) _Float16 Al[128 * 64];
    __shared__ __align__(16) _Float16 Bh2[128 * 64];
    __shared__ __align__(16) _Float16 Bl[128 * 64];

    const int tid  = threadIdx.x;
    const int t0   = blockIdx.y * 128;
    const int h0   = blockIdx.x * 128;
    const int lane = tid & 63;
    const int wave = tid >> 6;
    const int wrow = wave >> 1;
    const int wcol = wave & 1;
    const int ln15 = lane & 15;
    const int kq   = lane >> 4;

    f32x4 acc[4][4] = {};

    int baseA[4], swzA[4], baseB[4], swzB[4];
#pragma unroll
    for (int m = 0; m < 4; ++m) {
        int rA = wrow * 64 + m * 16 + ln15;
        baseA[m] = rA * 128; swzA[m] = (rA & 7) << 4;
        int rB = wcol * 64 + m * 16 + ln15;
        baseB[m] = rB * 128; swzB[m] = (rB & 7) << 4;
    }

    for (int kt = 0; kt < K_DIM / 64; ++kt) {
        const int k0 = kt * 64;
        __syncthreads();
#pragma unroll
        for (int t = 0; t < 4; ++t) {
            int cc  = tid + t * 256;
            int row = cc >> 3;
            int kc  = (cc & 7) * 8;
            size_t gA = (size_t)(t0 + row) * K_DIM + k0 + kc;
            size_t gB = (size_t)(h0 + row) * K_DIM + k0 + kc;
            float a[8], b[8];
            *(float4*)(a)     = *(const float4*)(X + gA);
            *(float4*)(a + 4) = *(const float4*)(X + gA + 4);
            *(float4*)(b)     = *(const float4*)(Bm + gB);
            *(float4*)(b + 4) = *(const float4*)(Bm + gB + 4);
            f16x8 ah, al, bh, bl;
#pragma unroll
            for (int j = 0; j < 8; ++j) {
                _Float16 hh = (_Float16)a[j];
                ah[j] = hh; al[j] = (_Float16)(a[j] - (float)hh);
                _Float16 gg = (_Float16)b[j];
                bh[j] = gg; bl[j] = (_Float16)(b[j] - (float)gg);
            }
            int off = row * 128 + ((kc * 2) ^ ((row & 7) << 4));
            *(f16x8*)((char*)Ah + off)  = ah;
            *(f16x8*)((char*)Al + off)  = al;
            *(f16x8*)((char*)Bh2 + off) = bh;
            *(f16x8*)((char*)Bl + off)  = bl;
        }
        __syncthreads();
#pragma unroll
        for (int kk = 0; kk < 2; ++kk) {
            const int kb2 = kk * 64 + kq * 16;
            f16x8 fa[4], fb[4], ft[4];
#pragma unroll
            for (int m = 0; m < 4; ++m)
                fa[m] = *(const f16x8*)((const char*)Ah + baseA[m] + (kb2 ^ swzA[m]));
#pragma unroll
            for (int m = 0; m < 4; ++m)
                fb[m] = *(const f16x8*)((const char*)Bh2 + baseB[m] + (kb2 ^ swzB[m]));
#pragma unroll
            for (int m = 0; m < 4; ++m)
#pragma unroll
                for (int n = 0; n < 4; ++n)
                    acc[m][n] = __builtin_amdgcn_mfma_f32_16x16x32_f16(fa[m], fb[n], acc[m][n], 0, 0, 0);
#pragma unroll
            for (int m = 0; m < 4; ++m)
                ft[m] = *(const f16x8*)((const char*)Bl + baseB[m] + (kb2 ^ swzB[m]));
#pragma unroll
            for (int m = 0; m < 4; ++m)
#pragma unroll
                for (int n = 0; n < 4; ++n)
                    acc[m][n] = __builtin_amdgcn_mfma_f32_16x16x32_f16(fa[m], ft[n], acc[m][n], 0, 0, 0);
#pragma unroll
            for (int m = 0; m < 4; ++m)
                ft[m] = *(const f16x8*)((const char*)Al + baseA[m] + (kb2 ^ swzA[m]));
#pragma unroll
            for (int m = 0; m < 4; ++m)
#pragma unroll
                for (int n = 0; n < 4; ++n)
                    acc[m][n] = __builtin_amdgcn_mfma_f32_16x16x32_f16(ft[m], fb[n], acc[m][n], 0, 0, 0);
        }
    }

#pragma unroll
    for (int m = 0; m < 4; ++m) {
        int row = t0 + wrow * 64 + m * 16 + kq * 4;
#pragma unroll
        for (int n = 0; n < 4; ++n) {
            int col = h0 + wcol * 64 + n * 16 + ln15;
#pragma unroll
            for (int j = 0; j < 4; ++j)
                Y[(size_t)(row + j) * H_DIM + col] = acc[m][n][j];
        }
    }
}

__global__ __launch_bounds__(256) void scanA(const float* __restrict__ Y,
                                             const float* __restrict__ lamda,
                                             float* __restrict__ e) {
    int c = blockIdx.x >> 3;
    int h = (blockIdx.x & 7) * 256 + threadIdx.x;
    float lam = lamda[h];
    float s = 0.f;
    const float* p = Y + (size_t)c * CLEN * H_DIM + h;
#pragma unroll
    for (int t = 0; t < CLEN; ++t) { s = fmaf(lam, s, *p); p += H_DIM; }
    e[(size_t)c * H_DIM + h] = s;
}

__global__ __launch_bounds__(256) void scanCB_plain(float* __restrict__ Y,
                                                    const float* __restrict__ lamda,
                                                    const float* __restrict__ e) {
    int c = blockIdx.x >> 3;
    int h = (blockIdx.x & 7) * 256 + threadIdx.x;
    float lam = lamda[h];
    float lamL = lam;
#pragma unroll
    for (int i = 0; i < 6; ++i) lamL *= lamL;
    float s = 0.f;
    for (int ci = 0; ci < c; ++ci)
        s = fmaf(lamL, s, e[(size_t)ci * H_DIM + h]);
    float* q = Y + (size_t)c * CLEN * H_DIM + h;
#pragma unroll
    for (int t = 0; t < CLEN; ++t) {
        float v = fmaf(lam, s, q[(size_t)t * H_DIM]);
        q[(size_t)t * H_DIM] = v;
        s = v;
    }
}

extern "C" void kernel_launch(void* const* d_in, const int* in_sizes, int n_in,
                              void* d_out, int out_size, void* d_ws, size_t ws_size,
                              hipStream_t stream) {
    const float* X   = (const float*)d_in[0];
    const float* lam = (const float*)d_in[1];
    const float* Bm  = (const float*)d_in[2];
    float* Y = (float*)d_out;

    const size_t needFused = (2 * nX + nB) * sizeof(_Float16)          // Xh+Bh+Yh
                           + (size_t)NCHUNK * H_DIM * sizeof(float);   // e 512KB

    if (ws_size >= needFused) {
        _Float16* Xh = (_Float16*)d_ws;
        _Float16* Bh = Xh + nX;
        _Float16* Yh = Bh + nB;
        float* e = (float*)(Yh + nX);

        int cvtBlocks = (int)((nX + nB) / 8 / 256);                    // 6144
        cvt_swz_all<<<dim3(cvtBlocks), 256, 0, stream>>>(X, Bm, Xh, Bh);
        gemm_f16<<<dim3(512), 512, 0, stream>>>(Xh, Bh, lam, Yh, e);
        scanCB<<<dim3(NCHUNK * 8), 256, 0, stream>>>(Yh, Y, lam, e);
    } else {
        dim3 grid(H_DIM / 128, T_DIM / 128);
        gemm_xbT_split<<<grid, 256, 0, stream>>>(X, Bm, Y);
        float* e = (float*)d_ws;   // needs 512KB only
        scanA<<<dim3(NCHUNK * 8), 256, 0, stream>>>(Y, lam, e);
        scanCB_plain<<<dim3(NCHUNK * 8), 256, 0, stream>>>(Y, lam, e);
    }
}

// Round 18
// 72.912 us; speedup vs baseline: 1.1690x; 1.1690x over previous
//
#include <hip/hip_runtime.h>
#include <hip/hip_bf16.h>

#define T_DIM 4096
#define H_DIM 2048
#define K_DIM 2048
#define NCHUNK 64
#define CLEN 64
#define NT (K_DIM / 64)

typedef float f32x4 __attribute__((ext_vector_type(4)));
typedef _Float16 f16x8 __attribute__((ext_vector_type(8)));

typedef const __attribute__((address_space(1))) char* gp1;
typedef __attribute__((address_space(3))) char* lp3;

static const size_t nX = (size_t)T_DIM * K_DIM;   // 8.4M elems
static const size_t nB = (size_t)H_DIM * K_DIM;   // 4.2M elems

// ---------------------------------------------------------------------------
// Convert pass: fp32 -> f16 (RN), PRE-SWIZZLED (16B block at byte colB ->
// colB ^ ((row&7)<<4) within each 128B row segment) so linear global_load_lds
// staging lands swizzled for free. [r4-proven; r17's 64B-segment variant
// caused 6.3M bank conflicts -> reverted]
// ---------------------------------------------------------------------------
__global__ __launch_bounds__(256) void cvt_swz_all(const float* __restrict__ X,
                                                   const float* __restrict__ Bm,
                                                   _Float16* __restrict__ Xh,
                                                   _Float16* __restrict__ Bh) {
    size_t i = ((size_t)blockIdx.x * 256 + threadIdx.x) * 8;
    const float* in;
    _Float16* out;
    size_t j;
    if (i < nX) { in = X;  out = Xh; j = i; }
    else        { in = Bm; out = Bh; j = i - nX; }
    int row  = (int)(j >> 11);
    int colB = (int)(j & 2047) * 2;
    float a[8];
    *(f32x4*)(a)     = *(const f32x4*)(in + j);
    *(f32x4*)(a + 4) = *(const f32x4*)(in + j + 4);
    f16x8 h;
#pragma unroll
    for (int k = 0; k < 8; ++k) h[k] = (_Float16)a[k];
    size_t ob = (size_t)row * 4096 + (size_t)(colB ^ ((row & 7) << 4));
    *(f16x8*)((char*)out + ob) = h;
}

// ---------------------------------------------------------------------------
// f16 GEMM, Y = X @ B^T, 128x128 tile, BK=64, 8 waves (512 thr), 2Mx2Nx2K
// wave split, prefetch dbuf + plain __syncthreads. 40.2us = 855 TF-equiv
// ~ 95% of the m97-structure ceiling (874-912 TF). Session A/Bs exhausted:
// counted-vmcnt graft -7% (r8); LDS-read cut neutral (r10); 256^2 split-K
// -30% (r15, 1 block/CU); BK=32 -42% (r17, 4-way LDS conflicts); coop
// fusion catastrophic (r12). This is the verified optimum for this shape.
// Y written f16 (r14). Epilogue: e[c][h] from fp32 accumulators.
// ---------------------------------------------------------------------------
__global__ __launch_bounds__(512, 4) void gemm_f16(const _Float16* __restrict__ Xh,
                                                   const _Float16* __restrict__ Bh,
                                                   const float* __restrict__ lamda,
                                                   _Float16* __restrict__ Yh,
                                                   float* __restrict__ e) {
    __shared__ __align__(16) _Float16 sMem[2][2][128 * 64];

    int bid = blockIdx.x;
    int swz = (bid & 7) * 64 + (bid >> 3);    // bijective: 512 % 8 == 0
    const int h0 = (swz & 15) * 128;
    const int t0 = (swz >> 4) * 128;

    const int tid  = threadIdx.x;
    const int lane = tid & 63;
    const int wave = tid >> 6;
    const int wrow = (wave >> 2) & 1;         // 64-row band (= one scan chunk)
    const int wcol = (wave >> 1) & 1;
    const int kks  = wave & 1;                // K=32 half owned by this wave
    const int ln15 = lane & 15;
    const int kq   = lane >> 4;

    f32x4 acc[4][4] = {};

    const int srow = tid >> 3;
    const int kcB  = (tid & 7) * 16;
    size_t gA0[2], gB0[2];
    unsigned ldsOff[2];
#pragma unroll
    for (int q = 0; q < 2; ++q) {
        gA0[q] = (size_t)(t0 + srow + q * 64) * 4096 + kcB;
        gB0[q] = (size_t)(h0 + srow + q * 64) * 4096 + kcB;
        ldsOff[q] = (unsigned)(q * 8192 + wave * 1024);
    }

    const int kb = kks * 64 + kq * 16;
    int offA[4], offB[4];
#pragma unroll
    for (int m = 0; m < 4; ++m) {
        int rA = wrow * 64 + m * 16 + ln15;
        offA[m] = rA * 128 + (kb ^ ((rA & 7) << 4));
        int rB = wcol * 64 + m * 16 + ln15;
        offB[m] = rB * 128 + (kb ^ ((rB & 7) << 4));
    }

#define STAGE(buf, kt)                                                                   \
    {                                                                                    \
        _Pragma("unroll")                                                                \
        for (int q = 0; q < 2; ++q) {                                                    \
            __builtin_amdgcn_global_load_lds((gp1)((const char*)Xh + gA0[q] + (kt) * 128), \
                                             (lp3)((char*)sMem[buf][0] + ldsOff[q]), 16, 0, 0); \
            __builtin_amdgcn_global_load_lds((gp1)((const char*)Bh + gB0[q] + (kt) * 128), \
                                             (lp3)((char*)sMem[buf][1] + ldsOff[q]), 16, 0, 0); \
        }                                                                                \
    }

#define COMPUTE(buf)                                                                     \
    {                                                                                    \
        const char* pA = (const char*)sMem[buf][0];                                      \
        const char* pB = (const char*)sMem[buf][1];                                      \
        f16x8 fa[4], fb[4];                                                              \
        _Pragma("unroll")                                                                \
        for (int m = 0; m < 4; ++m) fa[m] = *(const f16x8*)(pA + offA[m]);               \
        _Pragma("unroll")                                                                \
        for (int n = 0; n < 4; ++n) fb[n] = *(const f16x8*)(pB + offB[n]);               \
        _Pragma("unroll")                                                                \
        for (int m = 0; m < 4; ++m)                                                      \
            _Pragma("unroll")                                                            \
            for (int n = 0; n < 4; ++n)                                                  \
                acc[m][n] = __builtin_amdgcn_mfma_f32_16x16x32_f16(fa[m], fb[n],         \
                                                                  acc[m][n], 0, 0, 0);  \
    }

    STAGE(0, 0);
    __syncthreads();

    int cur = 0;
    for (int kt = 0; kt < NT; ++kt) {
        if (kt + 1 < NT) STAGE(cur ^ 1, kt + 1);
        COMPUTE(cur);
        __syncthreads();
        cur ^= 1;
    }
#undef STAGE
#undef COMPUTE

    // cross-kk reduction through freed staging LDS (conflict-free).
    const int p = wrow * 2 + wcol;
    float* red = (float*)sMem;
    if (kks == 1) {
#pragma unroll
        for (int m = 0; m < 4; ++m)
#pragma unroll
            for (int n = 0; n < 4; ++n)
                *(f32x4*)((char*)red + p * 16384 + (m * 4 + n) * 1024 + lane * 16) = acc[m][n];
    }
    __syncthreads();
    if (kks == 0) {
#pragma unroll
        for (int m = 0; m < 4; ++m)
#pragma unroll
            for (int n = 0; n < 4; ++n)
                acc[m][n] += *(const f32x4*)((const char*)red + p * 16384 + (m * 4 + n) * 1024 + lane * 16);

        // epilogue 1: Y-write (f16). C/D: col = lane&15, row = (lane>>4)*4+j
#pragma unroll
        for (int m = 0; m < 4; ++m) {
            int row = t0 + wrow * 64 + m * 16 + kq * 4;
#pragma unroll
            for (int n = 0; n < 4; ++n) {
                int col = h0 + wcol * 64 + n * 16 + ln15;
#pragma unroll
                for (int j = 0; j < 4; ++j)
                    Yh[(size_t)(row + j) * H_DIM + col] = (_Float16)acc[m][n][j];
            }
        }

        // epilogue 2: e[c][h] = sum_r lam^(63-r) y[r][h] for this wave's chunk.
        const int c = (t0 >> 6) + wrow;
#pragma unroll
        for (int n = 0; n < 4; ++n) {
            int col = h0 + wcol * 64 + n * 16 + ln15;
            float lam  = lamda[col];
            float lam2 = lam * lam;
            float lam4 = lam2 * lam2;
            float lam16 = lam4 * lam4 * lam4 * lam4;
            float hsum = 0.f;
#pragma unroll
            for (int m = 0; m < 4; ++m) {
                float hm = fmaf(fmaf(fmaf(acc[m][n][0], lam, acc[m][n][1]), lam,
                                     acc[m][n][2]), lam, acc[m][n][3]);
                hsum = fmaf(hsum, lam16, hm);
            }
            float w = 1.f;                     // lam4^(3-kq)
            if (kq < 3) w = lam4;
            if (kq < 2) w *= lam4;
            if (kq < 1) w *= lam4;
            float T = hsum * w;
            T += __shfl_xor(T, 16);
            T += __shfl_xor(T, 32);
            if (kq == 0) e[(size_t)c * H_DIM + col] = T;
        }
    }
}

// ---------------------------------------------------------------------------
// Scan finish: carry prefix P[c] from e (identical fma order every block),
// seeded chunk re-scan reading f16 Y, writing final fp32 h to d_out.
// ---------------------------------------------------------------------------
__global__ __launch_bounds__(256) void scanCB(const _Float16* __restrict__ Yh,
                                              float* __restrict__ Y,
                                              const float* __restrict__ lamda,
                                              const float* __restrict__ e) {
    int c = blockIdx.x >> 3;
    int h = (blockIdx.x & 7) * 256 + threadIdx.x;
    float lam = lamda[h];
    float lamL = lam;
#pragma unroll
    for (int i = 0; i < 6; ++i) lamL *= lamL;   // lam^64
    float s = 0.f;
    for (int ci = 0; ci < c; ++ci)
        s = fmaf(lamL, s, e[(size_t)ci * H_DIM + h]);   // s == P[c]
    const _Float16* qi = Yh + (size_t)c * CLEN * H_DIM + h;
    float* qo = Y + (size_t)c * CLEN * H_DIM + h;
#pragma unroll
    for (int t = 0; t < CLEN; ++t) {
        float v = fmaf(lam, s, (float)qi[(size_t)t * H_DIM]);
        qo[(size_t)t * H_DIM] = v;
        s = v;
    }
}

// ---------------------------------------------------------------------------
// Fallback path (ws too small): register-staged hi/lo split GEMM + scans,
// all through fp32 Y in d_out.
// ---------------------------------------------------------------------------
__global__ __launch_bounds__(256) void gemm_xbT_split(const float* __restrict__ X,
                                                      const float* __restrict__ Bm,
                                                      float* __restrict__ Y) {
    __shared__ __align__(16) _Float16 Ah[128 * 64];
    __shared__ __align__(16) _Float16 Al[128 * 64];
    __shared__ __align__(16) _Float16 Bh2[128 * 64];
    __shared__ __align__(16) _Float16 Bl[128 * 64];

    const int tid  = threadIdx.x;
    const int t0   = blockIdx.y * 128;
    const int h0   = blockIdx.x * 128;
    const int lane = tid & 63;
    const int wave = tid >> 6;
    const int wrow = wave >> 1;
    const int wcol = wave & 1;
    const int ln15 = lane & 15;
    const int kq   = lane >> 4;

    f32x4 acc[4][4] = {};

    int baseA[4], swzA[4], baseB[4], swzB[4];
#pragma unroll
    for (int m = 0; m < 4; ++m) {
        int rA = wrow * 64 + m * 16 + ln15;
        baseA[m] = rA * 128; swzA[m] = (rA & 7) << 4;
        int rB = wcol * 64 + m * 16 + ln15;
        baseB[m] = rB * 128; swzB[m] = (rB & 7) << 4;
    }

    for (int kt = 0; kt < NT; ++kt) {
        const int k0 = kt * 64;
        __syncthreads();
#pragma unroll
        for (int t = 0; t < 4; ++t) {
            int cc  = tid + t * 256;
            int row = cc >> 3;
            int kc  = (cc & 7) * 8;
            size_t gA = (size_t)(t0 + row) * K_DIM + k0 + kc;
            size_t gB = (size_t)(h0 + row) * K_DIM + k0 + kc;
            float a[8], b[8];
            *(float4*)(a)     = *(const float4*)(X + gA);
            *(float4*)(a + 4) = *(const float4*)(X + gA + 4);
            *(float4*)(b)     = *(const float4*)(Bm + gB);
            *(float4*)(b + 4) = *(const float4*)(Bm + gB + 4);
            f16x8 ah, al, bh, bl;
#pragma unroll
            for (int j = 0; j < 8; ++j) {
                _Float16 hh = (_Float16)a[j];
                ah[j] = hh; al[j] = (_Float16)(a[j] - (float)hh);
                _Float16 gg = (_Float16)b[j];
                bh[j] = gg; bl[j] = (_Float16)(b[j] - (float)gg);
            }
            int off = row * 128 + ((kc * 2) ^ ((row & 7) << 4));
            *(f16x8*)((char*)Ah + off)  = ah;
            *(f16x8*)((char*)Al + off)  = al;
            *(f16x8*)((char*)Bh2 + off) = bh;
            *(f16x8*)((char*)Bl + off)  = bl;
        }
        __syncthreads();
#pragma unroll
        for (int kk = 0; kk < 2; ++kk) {
            const int kb2 = kk * 64 + kq * 16;
            f16x8 fa[4], fb[4], ft[4];
#pragma unroll
            for (int m = 0; m < 4; ++m)
                fa[m] = *(const f16x8*)((const char*)Ah + baseA[m] + (kb2 ^ swzA[m]));
#pragma unroll
            for (int m = 0; m < 4; ++m)
                fb[m] = *(const f16x8*)((const char*)Bh2 + baseB[m] + (kb2 ^ swzB[m]));
#pragma unroll
            for (int m = 0; m < 4; ++m)
#pragma unroll
                for (int n = 0; n < 4; ++n)
                    acc[m][n] = __builtin_amdgcn_mfma_f32_16x16x32_f16(fa[m], fb[n], acc[m][n], 0, 0, 0);
#pragma unroll
            for (int m = 0; m < 4; ++m)
                ft[m] = *(const f16x8*)((const char*)Bl + baseB[m] + (kb2 ^ swzB[m]));
#pragma unroll
            for (int m = 0; m < 4; ++m)
#pragma unroll
                for (int n = 0; n < 4; ++n)
                    acc[m][n] = __builtin_amdgcn_mfma_f32_16x16x32_f16(fa[m], ft[n], acc[m][n], 0, 0, 0);
#pragma unroll
            for (int m = 0; m < 4; ++m)
                ft[m] = *(const f16x8*)((const char*)Al + baseA[m] + (kb2 ^ swzA[m]));
#pragma unroll
            for (int m = 0; m < 4; ++m)
#pragma unroll
                for (int n = 0; n < 4; ++n)
                    acc[m][n] = __builtin_amdgcn_mfma_f32_16x16x32_f16(ft[m], fb[n], acc[m][n], 0, 0, 0);
        }
    }

#pragma unroll
    for (int m = 0; m < 4; ++m) {
        int row = t0 + wrow * 64 + m * 16 + kq * 4;
#pragma unroll
        for (int n = 0; n < 4; ++n) {
            int col = h0 + wcol * 64 + n * 16 + ln15;
#pragma unroll
            for (int j = 0; j < 4; ++j)
                Y[(size_t)(row + j) * H_DIM + col] = acc[m][n][j];
        }
    }
}

__global__ __launch_bounds__(256) void scanA(const float* __restrict__ Y,
                                             const float* __restrict__ lamda,
                                             float* __restrict__ e) {
    int c = blockIdx.x >> 3;
    int h = (blockIdx.x & 7) * 256 + threadIdx.x;
    float lam = lamda[h];
    float s = 0.f;
    const float* p = Y + (size_t)c * CLEN * H_DIM + h;
#pragma unroll
    for (int t = 0; t < CLEN; ++t) { s = fmaf(lam, s, *p); p += H_DIM; }
    e[(size_t)c * H_DIM + h] = s;
}

__global__ __launch_bounds__(256) void scanCB_plain(float* __restrict__ Y,
                                                    const float* __restrict__ lamda,
                                                    const float* __restrict__ e) {
    int c = blockIdx.x >> 3;
    int h = (blockIdx.x & 7) * 256 + threadIdx.x;
    float lam = lamda[h];
    float lamL = lam;
#pragma unroll
    for (int i = 0; i < 6; ++i) lamL *= lamL;
    float s = 0.f;
    for (int ci = 0; ci < c; ++ci)
        s = fmaf(lamL, s, e[(size_t)ci * H_DIM + h]);
    float* q = Y + (size_t)c * CLEN * H_DIM + h;
#pragma unroll
    for (int t = 0; t < CLEN; ++t) {
        float v = fmaf(lam, s, q[(size_t)t * H_DIM]);
        q[(size_t)t * H_DIM] = v;
        s = v;
    }
}

extern "C" void kernel_launch(void* const* d_in, const int* in_sizes, int n_in,
                              void* d_out, int out_size, void* d_ws, size_t ws_size,
                              hipStream_t stream) {
    const float* X   = (const float*)d_in[0];
    const float* lam = (const float*)d_in[1];
    const float* Bm  = (const float*)d_in[2];
    float* Y = (float*)d_out;

    const size_t needFused = (2 * nX + nB) * sizeof(_Float16)          // Xh+Bh+Yh
                           + (size_t)NCHUNK * H_DIM * sizeof(float);   // e 512KB

    if (ws_size >= needFused) {
        _Float16* Xh = (_Float16*)d_ws;
        _Float16* Bh = Xh + nX;
        _Float16* Yh = Bh + nB;
        float* e = (float*)(Yh + nX);

        int cvtBlocks = (int)((nX + nB) / 8 / 256);                    // 6144
        cvt_swz_all<<<dim3(cvtBlocks), 256, 0, stream>>>(X, Bm, Xh, Bh);
        gemm_f16<<<dim3(512), 512, 0, stream>>>(Xh, Bh, lam, Yh, e);
        scanCB<<<dim3(NCHUNK * 8), 256, 0, stream>>>(Yh, Y, lam, e);
    } else {
        dim3 grid(H_DIM / 128, T_DIM / 128);
        gemm_xbT_split<<<grid, 256, 0, stream>>>(X, Bm, Y);
        float* e = (float*)d_ws;   // needs 512KB only
        scanA<<<dim3(NCHUNK * 8), 256, 0, stream>>>(Y, lam, e);
        scanCB_plain<<<dim3(NCHUNK * 8), 256, 0, stream>>>(Y, lam, e);
    }
}